// Round 7
// baseline (233.903 us; speedup 1.0000x reference)
//
#include <hip/hip_runtime.h>
#include <hip/hip_fp16.h>

// 2-layer GCN, N=100000, E=6400000 (+self-loops).
// Round 18: r5 structure, VPB 256->128 to kill block-count quantization in
// k_ag1 (391 blocks @ 2048thr/72.7KB = 1-resident-batch/CU -> 2 scheduling
// rounds, round 2 only 53% of CUs busy; measured Occupancy 30%). Now 782
// blocks @ 512thr/37KB = 4 blocks/CU -> ALL blocks co-resident, no rounds.
// Scat reverted to r1-proven 7-bit config (SCT=1024, MAXB=1024, EPB=12500,
// uniform 512 blocks) minus the deg atomics (r1 lesson). g2 remapped.
// No global atomics, no grid.sync. fp32 accumulation; fp16 quantization
// ~1e-4 abs err (thr 1.97e-3).

#define TPB 256
#define VPB 128            // nodes per bucket
#define B_BITS 7
#define MAXB 1024          // >= B=782, pow2 for scan
#define CAP 8960           // slab capacity: mean 8192, +~8.5 sigma
#define EPB 12500          // 512*12500 = 6.4M = E exactly
#define SCT 1024           // scat block size (must be >= MAXB for scan)
#define DGT 512            // pre block size
#define AGT 512            // ag1 block size (4 lanes x 128 nodes)

typedef int int4e __attribute__((ext_vector_type(4)));
typedef _Float16 h8 __attribute__((ext_vector_type(8)));

__device__ __forceinline__ int4e ld4(const int* p) {
    return *(const int4e*)p;
}

__global__ void k_init(int B, int* __restrict__ bpos) {
    int b = blockIdx.x * blockDim.x + threadIdx.x;
    if (b < B) bpos[b] = b * CAP;
}

// partition edges into bucket slabs, packed (src<<7 | local_dst).
// LDS-staged sort + coalesced burst writes. (r1-proven 7-bit config.)
__global__ __launch_bounds__(SCT) void k_scat(const int* __restrict__ src,
        const int* __restrict__ dst, int E, int B,
        int* __restrict__ bpos, int* __restrict__ pairs) {
    __shared__ int sorted[EPB];          // 50 KB
    __shared__ int hist[MAXB], scn[MAXB], cur[MAXB], gbase[MAXB];
    int t = threadIdx.x;
    for (int i = t; i < MAXB; i += SCT) hist[i] = 0;
    __syncthreads();
    int lo = blockIdx.x * EPB;
    int n = min(E - lo, EPB);
    int n4 = n & ~3;
    for (int i = t * 4; i < n4; i += SCT * 4) {
        int4e d4 = ld4(dst + lo + i);
        atomicAdd(&hist[d4.x >> B_BITS], 1);
        atomicAdd(&hist[d4.y >> B_BITS], 1);
        atomicAdd(&hist[d4.z >> B_BITS], 1);
        atomicAdd(&hist[d4.w >> B_BITS], 1);
    }
    for (int i = n4 + t; i < n; i += SCT)
        atomicAdd(&hist[dst[lo + i] >> B_BITS], 1);
    __syncthreads();
    if (t < MAXB) scn[t] = hist[t];
    __syncthreads();
    for (int off = 1; off < MAXB; off <<= 1) {
        int v = (t >= off && t < MAXB) ? scn[t - off] : 0;
        __syncthreads();
        if (t < MAXB) scn[t] += v;
        __syncthreads();
    }
    if (t < MAXB) {
        int h = hist[t];
        cur[t] = scn[t] - h;
        gbase[t] = (t < B && h) ? atomicAdd(&bpos[t], h) : 0;
    }
    __syncthreads();
    for (int i = t * 4; i < n4; i += SCT * 4) {
        int4e d4 = ld4(dst + lo + i);          // L2 hit (pass 1 warmed it)
        int4e s4 = ld4(src + lo + i);
        int p;
        p = atomicAdd(&cur[d4.x >> B_BITS], 1); sorted[p] = (s4.x << B_BITS) | (d4.x & (VPB - 1));
        p = atomicAdd(&cur[d4.y >> B_BITS], 1); sorted[p] = (s4.y << B_BITS) | (d4.y & (VPB - 1));
        p = atomicAdd(&cur[d4.z >> B_BITS], 1); sorted[p] = (s4.z << B_BITS) | (d4.z & (VPB - 1));
        p = atomicAdd(&cur[d4.w >> B_BITS], 1); sorted[p] = (s4.w << B_BITS) | (d4.w & (VPB - 1));
    }
    for (int i = n4 + t; i < n; i += SCT) {
        int d = dst[lo + i], s = src[lo + i];
        int p = atomicAdd(&cur[d >> B_BITS], 1);
        sorted[p] = (s << B_BITS) | (d & (VPB - 1));
    }
    __syncthreads();
    int wave = t >> 6, lane = t & 63;
    for (int bb = wave; bb < B; bb += (SCT >> 6)) {
        int h = hist[bb];
        int st = scn[bb] - h;
        int gb = gbase[bb];
        for (int j = lane; j < h; j += 64)
            pairs[gb + j] = sorted[st + j];
    }
}

// per bucket: ONE slab pass -> hist -> scan -> jinfo + dinv-scaled xs rows.
__global__ __launch_bounds__(DGT) void k_pre(const int* __restrict__ pairs,
        const int* __restrict__ bpos, const float* __restrict__ x,
        unsigned int* __restrict__ jinfo, _Float16* __restrict__ xs, int N) {
    __shared__ int hist[VPB];
    __shared__ int scn[VPB];
    int t = threadIdx.x, b = blockIdx.x;
    if (t < VPB) hist[t] = 0;
    __syncthreads();
    int base = b * CAP;
    int n = bpos[b] - base, n4 = n & ~3;
    for (int i = t * 4; i < n4; i += DGT * 4) {
        int4e p = ld4(pairs + base + i);
        atomicAdd(&hist[p.x & (VPB - 1)], 1);
        atomicAdd(&hist[p.y & (VPB - 1)], 1);
        atomicAdd(&hist[p.z & (VPB - 1)], 1);
        atomicAdd(&hist[p.w & (VPB - 1)], 1);
    }
    for (int i = n4 + t; i < n; i += DGT)
        atomicAdd(&hist[pairs[base + i] & (VPB - 1)], 1);
    __syncthreads();
    if (t < VPB) scn[t] = hist[t];
    __syncthreads();
    for (int off = 1; off < VPB; off <<= 1) {
        int v = (t >= off && t < VPB) ? scn[t - off] : 0;
        __syncthreads();
        if (t < VPB) scn[t] += v;
        __syncthreads();
    }
    int node = b * VPB + t;
    if (t < VPB && node < N) {
        int h = hist[t];
        int start = base + scn[t] - h;             // exclusive
        jinfo[node] = ((unsigned int)start << 9) | (unsigned int)h;
        float di = rsqrtf((float)(h + 1));          // +1 self-loop
        const float* xp = x + (size_t)node * 5;
        h8 v;
        v[0] = (_Float16)(xp[0] * di); v[1] = (_Float16)(xp[1] * di);
        v[2] = (_Float16)(xp[2] * di); v[3] = (_Float16)(xp[3] * di);
        v[4] = (_Float16)(xp[4] * di);
        v[5] = (_Float16)0.f; v[6] = (_Float16)0.f; v[7] = (_Float16)0.f;
        *(h8*)(xs + (size_t)node * 8) = v;
    }
}

// per bucket (512 thr, 4 blocks/CU, ALL blocks resident): counting-scatter
// slab into LDS csr, layer-1 gather from csr (4 lanes/node, unroll 8),
// W1/W2 epilogue -> h2s; sorted write-back last.
__global__ __launch_bounds__(AGT) void k_ag1(int* __restrict__ pairs,
        const int* __restrict__ bpos, const unsigned int* __restrict__ jinfo,
        const _Float16* __restrict__ xs, const float* __restrict__ b1,
        const float* __restrict__ W1, const float* __restrict__ W2,
        _Float16* __restrict__ h2s, int N) {
    __shared__ int csr[CAP];                 // 35840 B
    __shared__ int js[VPB], ct[VPB], cur[VPB];
    int t = threadIdx.x, b = blockIdx.x;
    int base = b * CAP;
    if (t < VPB) {
        int node = b * VPB + t;
        int s = 0, c = 0;
        if (node < N) {
            unsigned int u = jinfo[node];
            s = (int)(u >> 9) - base;     // local slab offset
            c = (int)(u & 511u);
        }
        js[t] = s; ct[t] = c; cur[t] = s;
    }
    __syncthreads();
    int n = bpos[b] - base, n4 = n & ~3;
    for (int i = t * 4; i < n4; i += AGT * 4) {
        int4e p = ld4(pairs + base + i);
        int q;
        q = atomicAdd(&cur[p.x & (VPB - 1)], 1); csr[q] = p.x >> B_BITS;
        q = atomicAdd(&cur[p.y & (VPB - 1)], 1); csr[q] = p.y >> B_BITS;
        q = atomicAdd(&cur[p.z & (VPB - 1)], 1); csr[q] = p.z >> B_BITS;
        q = atomicAdd(&cur[p.w & (VPB - 1)], 1); csr[q] = p.w >> B_BITS;
    }
    for (int i = n4 + t; i < n; i += AGT) {
        int p = pairs[base + i];
        int q = atomicAdd(&cur[p & (VPB - 1)], 1);
        csr[q] = p >> B_BITS;
    }
    __syncthreads();
    // gather (latency-critical): 4 lanes/node, 5 channels, unroll 8
    int lane = t & 3, ln = t >> 2;
    int node = b * VPB + ln;
    int s0 = js[ln], cn = ct[ln];
    float a0 = 0.f, a1 = 0.f, a2 = 0.f, a3 = 0.f, a4 = 0.f;
    int j = lane;
    for (; j + 28 < cn; j += 32) {
        int sA = csr[s0 + j];      int sB = csr[s0 + j + 4];
        int sC = csr[s0 + j + 8];  int sD = csr[s0 + j + 12];
        int sE = csr[s0 + j + 16]; int sF = csr[s0 + j + 20];
        int sG = csr[s0 + j + 24]; int sH = csr[s0 + j + 28];
        h8 vA = *(const h8*)(xs + (size_t)sA * 8);
        h8 vB = *(const h8*)(xs + (size_t)sB * 8);
        h8 vC = *(const h8*)(xs + (size_t)sC * 8);
        h8 vD = *(const h8*)(xs + (size_t)sD * 8);
        h8 vE = *(const h8*)(xs + (size_t)sE * 8);
        h8 vF = *(const h8*)(xs + (size_t)sF * 8);
        h8 vG = *(const h8*)(xs + (size_t)sG * 8);
        h8 vH = *(const h8*)(xs + (size_t)sH * 8);
        a0 += ((float)vA[0] + (float)vB[0]) + ((float)vC[0] + (float)vD[0])
            + ((float)vE[0] + (float)vF[0]) + ((float)vG[0] + (float)vH[0]);
        a1 += ((float)vA[1] + (float)vB[1]) + ((float)vC[1] + (float)vD[1])
            + ((float)vE[1] + (float)vF[1]) + ((float)vG[1] + (float)vH[1]);
        a2 += ((float)vA[2] + (float)vB[2]) + ((float)vC[2] + (float)vD[2])
            + ((float)vE[2] + (float)vF[2]) + ((float)vG[2] + (float)vH[2]);
        a3 += ((float)vA[3] + (float)vB[3]) + ((float)vC[3] + (float)vD[3])
            + ((float)vE[3] + (float)vF[3]) + ((float)vG[3] + (float)vH[3]);
        a4 += ((float)vA[4] + (float)vB[4]) + ((float)vC[4] + (float)vD[4])
            + ((float)vE[4] + (float)vF[4]) + ((float)vG[4] + (float)vH[4]);
    }
    for (; j + 12 < cn; j += 16) {
        int sA = csr[s0 + j];      int sB = csr[s0 + j + 4];
        int sC = csr[s0 + j + 8];  int sD = csr[s0 + j + 12];
        h8 vA = *(const h8*)(xs + (size_t)sA * 8);
        h8 vB = *(const h8*)(xs + (size_t)sB * 8);
        h8 vC = *(const h8*)(xs + (size_t)sC * 8);
        h8 vD = *(const h8*)(xs + (size_t)sD * 8);
        a0 += (float)vA[0] + (float)vB[0] + (float)vC[0] + (float)vD[0];
        a1 += (float)vA[1] + (float)vB[1] + (float)vC[1] + (float)vD[1];
        a2 += (float)vA[2] + (float)vB[2] + (float)vC[2] + (float)vD[2];
        a3 += (float)vA[3] + (float)vB[3] + (float)vC[3] + (float)vD[3];
        a4 += (float)vA[4] + (float)vB[4] + (float)vC[4] + (float)vD[4];
    }
    for (; j < cn; j += 4) {
        int sA = csr[s0 + j];
        h8 vA = *(const h8*)(xs + (size_t)sA * 8);
        a0 += (float)vA[0]; a1 += (float)vA[1]; a2 += (float)vA[2];
        a3 += (float)vA[3]; a4 += (float)vA[4];
    }
#pragma unroll
    for (int d = 1; d < 4; d <<= 1) {
        a0 += __shfl_xor(a0, d); a1 += __shfl_xor(a1, d);
        a2 += __shfl_xor(a2, d); a3 += __shfl_xor(a3, d);
        a4 += __shfl_xor(a4, d);
    }
    if (node < N) {
        // self term (fp16 row) + epilogue
        h8 sv = *(const h8*)(xs + (size_t)node * 8);
        float tc[5];
        tc[0] = a0 + (float)sv[0]; tc[1] = a1 + (float)sv[1];
        tc[2] = a2 + (float)sv[2]; tc[3] = a3 + (float)sv[3];
        tc[4] = a4 + (float)sv[4];
        float di = rsqrtf((float)(cn + 1));
        float o1[8];
#pragma unroll
        for (int jj = 0; jj < 8; ++jj) {
            float h = 0.f;
#pragma unroll
            for (int c = 0; c < 5; ++c) h += tc[c] * W1[c * 8 + jj];
            o1[jj] = h * di + b1[jj];
        }
        if (lane == 0) {
            float hv[5];
#pragma unroll
            for (int k = 0; k < 5; ++k) {
                float h = 0.f;
#pragma unroll
                for (int jj = 0; jj < 8; ++jj) h += o1[jj] * W2[jj * 5 + k];
                hv[k] = h * di;
            }
            h8 w;
            w[0] = (_Float16)hv[0]; w[1] = (_Float16)hv[1]; w[2] = (_Float16)hv[2];
            w[3] = (_Float16)hv[3]; w[4] = (_Float16)hv[4];
            w[5] = (_Float16)0.f; w[6] = (_Float16)0.f; w[7] = (_Float16)0.f;
            *(h8*)(h2s + (size_t)node * 8) = w;
        }
    }
    // sorted write-back last (plain stores -> this XCD's L2 for k_g2)
    for (int i = t; i < n; i += AGT)
        pairs[base + i] = csr[i];
}

// g2 block swizzle: groups of 16 blocks cover 8 buckets x 2 sub-blocks
// such that XCD(blockIdx%8) == bucket%8 == ag1's writer XCD.
__device__ __forceinline__ void g_map(int g, int t, int* node, int* lane) {
    int q = g >> 4, r = g & 15;
    int b = q * 8 + (r & 7);       // bucket
    int s = r >> 3;                // sub-block within bucket (0..1)
    *node = b * VPB + s * 64 + (t >> 2);
    *lane = t & 3;
}

// layer 2: flat gather, 4 lanes/node, pipelined -> out fp32 + b2.
__global__ __launch_bounds__(TPB) void k_g2(const int* __restrict__ pairs,
        const unsigned int* __restrict__ jinfo, const _Float16* __restrict__ h2s,
        const float* __restrict__ b2, float* __restrict__ out, int N) {
    int node, lane;
    g_map(blockIdx.x, threadIdx.x, &node, &lane);
    if (node >= N) return;
    unsigned int u = jinfo[node];
    int jsa = (int)(u >> 9), cn = (int)(u & 511u);
    float a0 = 0.f, a1 = 0.f, a2 = 0.f, a3 = 0.f, a4 = 0.f;
    int j = lane;
    if (j + 12 < cn) {
        int iA = pairs[jsa + j],     iB = pairs[jsa + j + 4];
        int iC = pairs[jsa + j + 8], iD = pairs[jsa + j + 12];
        for (;;) {
            int nj = j + 16;
            bool more = (nj + 12 < cn);
            int pA, pB, pC, pD;
            if (more) {
                pA = pairs[jsa + nj];     pB = pairs[jsa + nj + 4];
                pC = pairs[jsa + nj + 8]; pD = pairs[jsa + nj + 12];
            }
            h8 vA = *(const h8*)(h2s + (size_t)iA * 8);
            h8 vB = *(const h8*)(h2s + (size_t)iB * 8);
            h8 vC = *(const h8*)(h2s + (size_t)iC * 8);
            h8 vD = *(const h8*)(h2s + (size_t)iD * 8);
            a0 += (float)vA[0] + (float)vB[0] + (float)vC[0] + (float)vD[0];
            a1 += (float)vA[1] + (float)vB[1] + (float)vC[1] + (float)vD[1];
            a2 += (float)vA[2] + (float)vB[2] + (float)vC[2] + (float)vD[2];
            a3 += (float)vA[3] + (float)vB[3] + (float)vC[3] + (float)vD[3];
            a4 += (float)vA[4] + (float)vB[4] + (float)vC[4] + (float)vD[4];
            if (!more) break;
            iA = pA; iB = pB; iC = pC; iD = pD; j = nj;
        }
        j += 16;
    }
    for (; j < cn; j += 4) {
        int sA = pairs[jsa + j];
        h8 vA = *(const h8*)(h2s + (size_t)sA * 8);
        a0 += (float)vA[0]; a1 += (float)vA[1]; a2 += (float)vA[2];
        a3 += (float)vA[3]; a4 += (float)vA[4];
    }
#pragma unroll
    for (int d = 1; d < 4; d <<= 1) {
        a0 += __shfl_xor(a0, d); a1 += __shfl_xor(a1, d);
        a2 += __shfl_xor(a2, d); a3 += __shfl_xor(a3, d);
        a4 += __shfl_xor(a4, d);
    }
    if (lane == 0) {
        float di = rsqrtf((float)(cn + 1));
        h8 sv = *(const h8*)(h2s + (size_t)node * 8);
        float* op = out + (size_t)node * 5;
        op[0] = (a0 + (float)sv[0]) * di + b2[0];
        op[1] = (a1 + (float)sv[1]) * di + b2[1];
        op[2] = (a2 + (float)sv[2]) * di + b2[2];
        op[3] = (a3 + (float)sv[3]) * di + b2[3];
        op[4] = (a4 + (float)sv[4]) * di + b2[4];
    }
}

extern "C" void kernel_launch(void* const* d_in, const int* in_sizes, int n_in,
                              void* d_out, int out_size, void* d_ws, size_t ws_size,
                              hipStream_t stream) {
    const float* x   = (const float*)d_in[0];
    const int*  eidx = (const int*)d_in[1];
    const float* W1 = (const float*)d_in[4];
    const float* b1 = (const float*)d_in[5];
    const float* W2 = (const float*)d_in[6];
    const float* b2 = (const float*)d_in[7];
    float* out = (float*)d_out;

    const int N = in_sizes[0] / 5;
    const int E = in_sizes[1] / 2;
    const int* src = eidx;
    const int* dst = eidx + E;

    const int B = (N + VPB - 1) / VPB;       // 782
    const int NBLK_E = (E + EPB - 1) / EPB;  // 512

    // workspace: pairs[B*CAP] xs[8N fp16] h2s[8N fp16] jinfo[N] bpos[B]
    int*      pairs = (int*)d_ws;
    _Float16* xs    = (_Float16*)(pairs + (size_t)B * CAP);
    _Float16* h2s   = xs + (size_t)8 * N;
    unsigned int* jinfo = (unsigned int*)(h2s + (size_t)8 * N);
    int*      bpos  = (int*)(jinfo + N);

    // g2 grid: 16-block groups covering 8 buckets x 2 sub-blocks,
    // so XCD(block%8) == bucket%8; ceil(B/8) groups.
    const int gG = ((B + 7) / 8) * 16;       // 98*16 = 1568

    k_init <<<(B + TPB - 1) / TPB, TPB, 0, stream>>>(B, bpos);
    k_scat <<<NBLK_E, SCT, 0, stream>>>(src, dst, E, B, bpos, pairs);
    k_pre  <<<B, DGT, 0, stream>>>(pairs, bpos, x, jinfo, xs, N);
    k_ag1  <<<B, AGT, 0, stream>>>(pairs, bpos, jinfo, xs, b1, W1, W2, h2s, N);
    k_g2   <<<gG, TPB, 0, stream>>>(pairs, jinfo, h2s, b2, out, N);
}

// Round 8
// 224.710 us; speedup vs baseline: 1.0409x; 1.0409x over previous
//
#include <hip/hip_runtime.h>
#include <hip/hip_fp16.h>

// 2-layer GCN, N=100000, E=6400000 (+self-loops).
// Round 19: best-of-breed consolidation across r5-r7 (no new structure):
//  k_scat: r5 8-bit config (SCT=512/MAXB=512/EPB=12500) - best measured.
//  k_pre : r5 (ONE slab pass -> hist -> scan -> jinfo + fp16 xs rows).
//  k_ag1 : r6 (VPB=256, gather-first / sorted-writeback-LAST, unroll 8) -
//          best measured ag1 (41.4us). NOT occupancy-bound (r7 refuted:
//          VPB=128 raised occ 30->39% with zero time change; ag1 = serial
//          phase-sum: slab read + LDS scatter + addr-rate-bound gather).
//  k_g2  : r4/r5 8-lane swizzled pipelined flat gather.
// No global atomics (r1), no grid.sync (r2), plain loads for L2 reuse +
// XCD-aligned swizzle (r4). fp32 accum; fp16 quant ~1e-4 err (thr 1.97e-3).

#define TPB 256
#define VPB 256            // nodes per bucket
#define B_BITS 8
#define MAXB 512           // >= B=391, pow2 for scan
#define CAP 17408          // slab capacity: mean 16368, +~8 sigma
#define EPB 12500          // 512*12500 = 6.4M = E exactly
#define SCT 512            // scat block size
#define DGT 512            // pre block size

typedef int int4e __attribute__((ext_vector_type(4)));
typedef _Float16 h8 __attribute__((ext_vector_type(8)));

__device__ __forceinline__ int4e ld4(const int* p) {
    return *(const int4e*)p;
}

__global__ void k_init(int B, int* __restrict__ bpos) {
    int b = blockIdx.x * blockDim.x + threadIdx.x;
    if (b < B) bpos[b] = b * CAP;
}

// partition edges into bucket slabs, packed (src<<8 | local_dst).
// LDS-staged sort + coalesced burst writes; plain loads so the 2nd dst pass
// L2-hits (each block re-reads its own 50KB chunk).
__global__ __launch_bounds__(SCT) void k_scat(const int* __restrict__ src,
        const int* __restrict__ dst, int E, int B,
        int* __restrict__ bpos, int* __restrict__ pairs) {
    __shared__ int sorted[EPB];          // 50 KB
    __shared__ int hist[MAXB], scn[MAXB], cur[MAXB], gbase[MAXB];
    int t = threadIdx.x;
    for (int i = t; i < MAXB; i += SCT) hist[i] = 0;
    __syncthreads();
    int lo = blockIdx.x * EPB;
    int n = min(E - lo, EPB);
    int n4 = n & ~3;
    for (int i = t * 4; i < n4; i += SCT * 4) {
        int4e d4 = ld4(dst + lo + i);
        atomicAdd(&hist[d4.x >> B_BITS], 1);
        atomicAdd(&hist[d4.y >> B_BITS], 1);
        atomicAdd(&hist[d4.z >> B_BITS], 1);
        atomicAdd(&hist[d4.w >> B_BITS], 1);
    }
    for (int i = n4 + t; i < n; i += SCT)
        atomicAdd(&hist[dst[lo + i] >> B_BITS], 1);
    __syncthreads();
    if (t < MAXB) scn[t] = hist[t];
    __syncthreads();
    for (int off = 1; off < MAXB; off <<= 1) {
        int v = (t >= off && t < MAXB) ? scn[t - off] : 0;
        __syncthreads();
        if (t < MAXB) scn[t] += v;
        __syncthreads();
    }
    if (t < MAXB) {
        int h = hist[t];
        cur[t] = scn[t] - h;
        gbase[t] = (t < B && h) ? atomicAdd(&bpos[t], h) : 0;
    }
    __syncthreads();
    for (int i = t * 4; i < n4; i += SCT * 4) {
        int4e d4 = ld4(dst + lo + i);          // L2 hit (pass 1 warmed it)
        int4e s4 = ld4(src + lo + i);
        int p;
        p = atomicAdd(&cur[d4.x >> B_BITS], 1); sorted[p] = (s4.x << B_BITS) | (d4.x & (VPB - 1));
        p = atomicAdd(&cur[d4.y >> B_BITS], 1); sorted[p] = (s4.y << B_BITS) | (d4.y & (VPB - 1));
        p = atomicAdd(&cur[d4.z >> B_BITS], 1); sorted[p] = (s4.z << B_BITS) | (d4.z & (VPB - 1));
        p = atomicAdd(&cur[d4.w >> B_BITS], 1); sorted[p] = (s4.w << B_BITS) | (d4.w & (VPB - 1));
    }
    for (int i = n4 + t; i < n; i += SCT) {
        int d = dst[lo + i], s = src[lo + i];
        int p = atomicAdd(&cur[d >> B_BITS], 1);
        sorted[p] = (s << B_BITS) | (d & (VPB - 1));
    }
    __syncthreads();
    int wave = t >> 6, lane = t & 63;
    for (int bb = wave; bb < B; bb += (SCT >> 6)) {
        int h = hist[bb];
        int st = scn[bb] - h;
        int gb = gbase[bb];
        for (int j = lane; j < h; j += 64)
            pairs[gb + j] = sorted[st + j];
    }
}

// per bucket: ONE slab pass -> hist -> scan -> jinfo + dinv-scaled xs rows.
__global__ __launch_bounds__(DGT) void k_pre(const int* __restrict__ pairs,
        const int* __restrict__ bpos, const float* __restrict__ x,
        unsigned int* __restrict__ jinfo, _Float16* __restrict__ xs, int N) {
    __shared__ int hist[VPB];
    __shared__ int scn[VPB];
    int t = threadIdx.x, b = blockIdx.x;
    if (t < VPB) hist[t] = 0;
    __syncthreads();
    int base = b * CAP;
    int n = bpos[b] - base, n4 = n & ~3;
    for (int i = t * 4; i < n4; i += DGT * 4) {
        int4e p = ld4(pairs + base + i);
        atomicAdd(&hist[p.x & (VPB - 1)], 1);
        atomicAdd(&hist[p.y & (VPB - 1)], 1);
        atomicAdd(&hist[p.z & (VPB - 1)], 1);
        atomicAdd(&hist[p.w & (VPB - 1)], 1);
    }
    for (int i = n4 + t; i < n; i += DGT)
        atomicAdd(&hist[pairs[base + i] & (VPB - 1)], 1);
    __syncthreads();
    if (t < VPB) scn[t] = hist[t];
    __syncthreads();
    for (int off = 1; off < VPB; off <<= 1) {
        int v = (t >= off && t < VPB) ? scn[t - off] : 0;
        __syncthreads();
        if (t < VPB) scn[t] += v;
        __syncthreads();
    }
    int node = b * VPB + t;
    if (t < VPB && node < N) {
        int h = hist[t];
        int start = base + scn[t] - h;             // exclusive
        jinfo[node] = ((unsigned int)start << 9) | (unsigned int)h;
        float di = rsqrtf((float)(h + 1));          // +1 self-loop
        const float* xp = x + (size_t)node * 5;
        h8 v;
        v[0] = (_Float16)(xp[0] * di); v[1] = (_Float16)(xp[1] * di);
        v[2] = (_Float16)(xp[2] * di); v[3] = (_Float16)(xp[3] * di);
        v[4] = (_Float16)(xp[4] * di);
        v[5] = (_Float16)0.f; v[6] = (_Float16)0.f; v[7] = (_Float16)0.f;
        *(h8*)(xs + (size_t)node * 8) = v;
    }
}

// per bucket (1024 thr): counting-scatter slab into LDS csr (starts from
// jinfo), layer-1 gather from LDS csr (4 lanes/node, unroll 8), W1/W2
// epilogue -> h2s; sorted write-back LAST (fire-and-forget stores).
__global__ __launch_bounds__(1024) void k_ag1(int* __restrict__ pairs,
        const int* __restrict__ bpos, const unsigned int* __restrict__ jinfo,
        const _Float16* __restrict__ xs, const float* __restrict__ b1,
        const float* __restrict__ W1, const float* __restrict__ W2,
        _Float16* __restrict__ h2s, int N) {
    __shared__ int csr[CAP];                 // 69632 B
    __shared__ int js[VPB], ct[VPB], cur[VPB];
    int t = threadIdx.x, b = blockIdx.x;
    int base = b * CAP;
    if (t < VPB) {
        int node = b * VPB + t;
        int s = 0, c = 0;
        if (node < N) {
            unsigned int u = jinfo[node];
            s = (int)(u >> 9) - base;     // local slab offset
            c = (int)(u & 511u);
        }
        js[t] = s; ct[t] = c; cur[t] = s;
    }
    __syncthreads();
    int n = bpos[b] - base, n4 = n & ~3;
    for (int i = t * 4; i < n4; i += 1024 * 4) {
        int4e p = ld4(pairs + base + i);
        int q;
        q = atomicAdd(&cur[p.x & (VPB - 1)], 1); csr[q] = p.x >> B_BITS;
        q = atomicAdd(&cur[p.y & (VPB - 1)], 1); csr[q] = p.y >> B_BITS;
        q = atomicAdd(&cur[p.z & (VPB - 1)], 1); csr[q] = p.z >> B_BITS;
        q = atomicAdd(&cur[p.w & (VPB - 1)], 1); csr[q] = p.w >> B_BITS;
    }
    for (int i = n4 + t; i < n; i += 1024) {
        int p = pairs[base + i];
        int q = atomicAdd(&cur[p & (VPB - 1)], 1);
        csr[q] = p >> B_BITS;
    }
    __syncthreads();
    // gather FIRST (latency-critical): 4 lanes/node, 5 channels, unroll 8
    int lane = t & 3, ln = t >> 2;
    int node = b * VPB + ln;
    int s0 = js[ln], cn = ct[ln];
    float a0 = 0.f, a1 = 0.f, a2 = 0.f, a3 = 0.f, a4 = 0.f;
    int j = lane;
    for (; j + 28 < cn; j += 32) {
        int sA = csr[s0 + j];      int sB = csr[s0 + j + 4];
        int sC = csr[s0 + j + 8];  int sD = csr[s0 + j + 12];
        int sE = csr[s0 + j + 16]; int sF = csr[s0 + j + 20];
        int sG = csr[s0 + j + 24]; int sH = csr[s0 + j + 28];
        h8 vA = *(const h8*)(xs + (size_t)sA * 8);
        h8 vB = *(const h8*)(xs + (size_t)sB * 8);
        h8 vC = *(const h8*)(xs + (size_t)sC * 8);
        h8 vD = *(const h8*)(xs + (size_t)sD * 8);
        h8 vE = *(const h8*)(xs + (size_t)sE * 8);
        h8 vF = *(const h8*)(xs + (size_t)sF * 8);
        h8 vG = *(const h8*)(xs + (size_t)sG * 8);
        h8 vH = *(const h8*)(xs + (size_t)sH * 8);
        a0 += ((float)vA[0] + (float)vB[0]) + ((float)vC[0] + (float)vD[0])
            + ((float)vE[0] + (float)vF[0]) + ((float)vG[0] + (float)vH[0]);
        a1 += ((float)vA[1] + (float)vB[1]) + ((float)vC[1] + (float)vD[1])
            + ((float)vE[1] + (float)vF[1]) + ((float)vG[1] + (float)vH[1]);
        a2 += ((float)vA[2] + (float)vB[2]) + ((float)vC[2] + (float)vD[2])
            + ((float)vE[2] + (float)vF[2]) + ((float)vG[2] + (float)vH[2]);
        a3 += ((float)vA[3] + (float)vB[3]) + ((float)vC[3] + (float)vD[3])
            + ((float)vE[3] + (float)vF[3]) + ((float)vG[3] + (float)vH[3]);
        a4 += ((float)vA[4] + (float)vB[4]) + ((float)vC[4] + (float)vD[4])
            + ((float)vE[4] + (float)vF[4]) + ((float)vG[4] + (float)vH[4]);
    }
    for (; j + 12 < cn; j += 16) {
        int sA = csr[s0 + j];      int sB = csr[s0 + j + 4];
        int sC = csr[s0 + j + 8];  int sD = csr[s0 + j + 12];
        h8 vA = *(const h8*)(xs + (size_t)sA * 8);
        h8 vB = *(const h8*)(xs + (size_t)sB * 8);
        h8 vC = *(const h8*)(xs + (size_t)sC * 8);
        h8 vD = *(const h8*)(xs + (size_t)sD * 8);
        a0 += (float)vA[0] + (float)vB[0] + (float)vC[0] + (float)vD[0];
        a1 += (float)vA[1] + (float)vB[1] + (float)vC[1] + (float)vD[1];
        a2 += (float)vA[2] + (float)vB[2] + (float)vC[2] + (float)vD[2];
        a3 += (float)vA[3] + (float)vB[3] + (float)vC[3] + (float)vD[3];
        a4 += (float)vA[4] + (float)vB[4] + (float)vC[4] + (float)vD[4];
    }
    for (; j < cn; j += 4) {
        int sA = csr[s0 + j];
        h8 vA = *(const h8*)(xs + (size_t)sA * 8);
        a0 += (float)vA[0]; a1 += (float)vA[1]; a2 += (float)vA[2];
        a3 += (float)vA[3]; a4 += (float)vA[4];
    }
#pragma unroll
    for (int d = 1; d < 4; d <<= 1) {
        a0 += __shfl_xor(a0, d); a1 += __shfl_xor(a1, d);
        a2 += __shfl_xor(a2, d); a3 += __shfl_xor(a3, d);
        a4 += __shfl_xor(a4, d);
    }
    if (node < N) {
        // self term (fp16 row) + epilogue
        h8 sv = *(const h8*)(xs + (size_t)node * 8);
        float tc[5];
        tc[0] = a0 + (float)sv[0]; tc[1] = a1 + (float)sv[1];
        tc[2] = a2 + (float)sv[2]; tc[3] = a3 + (float)sv[3];
        tc[4] = a4 + (float)sv[4];
        float di = rsqrtf((float)(cn + 1));
        float o1[8];
#pragma unroll
        for (int jj = 0; jj < 8; ++jj) {
            float h = 0.f;
#pragma unroll
            for (int c = 0; c < 5; ++c) h += tc[c] * W1[c * 8 + jj];
            o1[jj] = h * di + b1[jj];
        }
        if (lane == 0) {
            float hv[5];
#pragma unroll
            for (int k = 0; k < 5; ++k) {
                float h = 0.f;
#pragma unroll
                for (int jj = 0; jj < 8; ++jj) h += o1[jj] * W2[jj * 5 + k];
                hv[k] = h * di;
            }
            h8 w;
            w[0] = (_Float16)hv[0]; w[1] = (_Float16)hv[1]; w[2] = (_Float16)hv[2];
            w[3] = (_Float16)hv[3]; w[4] = (_Float16)hv[4];
            w[5] = (_Float16)0.f; w[6] = (_Float16)0.f; w[7] = (_Float16)0.f;
            *(h8*)(h2s + (size_t)node * 8) = w;
        }
    }
    // sorted write-back LAST (csr unmodified since barrier; stores drain
    // by kernel end; plain stores -> this XCD's L2 for k_g2's readers)
    for (int i = t; i < n; i += 1024)
        pairs[base + i] = csr[i];
}

// g2 block swizzle: groups of 64 blocks cover 8 buckets x 8 sub-blocks
// such that XCD(blockIdx%8) == bucket%8 == ag1's writer XCD.
__device__ __forceinline__ void g_map(int g, int t, int* node, int* lane) {
    int q = g >> 6, r = g & 63;
    int b = q * 8 + (r & 7);       // bucket
    int s = r >> 3;                // sub-block within bucket
    *node = b * VPB + s * 32 + (t >> 3);
    *lane = t & 7;
}

// layer 2: flat gather, 8 lanes/node, pipelined -> out fp32 + b2.
__global__ __launch_bounds__(TPB) void k_g2(const int* __restrict__ pairs,
        const unsigned int* __restrict__ jinfo, const _Float16* __restrict__ h2s,
        const float* __restrict__ b2, float* __restrict__ out, int N) {
    int node, lane;
    g_map(blockIdx.x, threadIdx.x, &node, &lane);
    if (node >= N) return;
    unsigned int u = jinfo[node];
    int jsa = (int)(u >> 9), cn = (int)(u & 511u);
    float a0 = 0.f, a1 = 0.f, a2 = 0.f, a3 = 0.f, a4 = 0.f;
    int j = lane;
    if (j + 24 < cn) {
        int iA = pairs[jsa + j],      iB = pairs[jsa + j + 8];
        int iC = pairs[jsa + j + 16], iD = pairs[jsa + j + 24];
        for (;;) {
            int nj = j + 32;
            bool more = (nj + 24 < cn);
            int pA, pB, pC, pD;
            if (more) {
                pA = pairs[jsa + nj];      pB = pairs[jsa + nj + 8];
                pC = pairs[jsa + nj + 16]; pD = pairs[jsa + nj + 24];
            }
            h8 vA = *(const h8*)(h2s + (size_t)iA * 8);
            h8 vB = *(const h8*)(h2s + (size_t)iB * 8);
            h8 vC = *(const h8*)(h2s + (size_t)iC * 8);
            h8 vD = *(const h8*)(h2s + (size_t)iD * 8);
            a0 += (float)vA[0] + (float)vB[0] + (float)vC[0] + (float)vD[0];
            a1 += (float)vA[1] + (float)vB[1] + (float)vC[1] + (float)vD[1];
            a2 += (float)vA[2] + (float)vB[2] + (float)vC[2] + (float)vD[2];
            a3 += (float)vA[3] + (float)vB[3] + (float)vC[3] + (float)vD[3];
            a4 += (float)vA[4] + (float)vB[4] + (float)vC[4] + (float)vD[4];
            if (!more) break;
            iA = pA; iB = pB; iC = pC; iD = pD; j = nj;
        }
        j += 32;
    }
    for (; j < cn; j += 8) {
        int sA = pairs[jsa + j];
        h8 vA = *(const h8*)(h2s + (size_t)sA * 8);
        a0 += (float)vA[0]; a1 += (float)vA[1]; a2 += (float)vA[2];
        a3 += (float)vA[3]; a4 += (float)vA[4];
    }
#pragma unroll
    for (int d = 1; d < 8; d <<= 1) {
        a0 += __shfl_xor(a0, d); a1 += __shfl_xor(a1, d);
        a2 += __shfl_xor(a2, d); a3 += __shfl_xor(a3, d);
        a4 += __shfl_xor(a4, d);
    }
    if (lane == 0) {
        float di = rsqrtf((float)(cn + 1));
        h8 sv = *(const h8*)(h2s + (size_t)node * 8);
        float* op = out + (size_t)node * 5;
        op[0] = (a0 + (float)sv[0]) * di + b2[0];
        op[1] = (a1 + (float)sv[1]) * di + b2[1];
        op[2] = (a2 + (float)sv[2]) * di + b2[2];
        op[3] = (a3 + (float)sv[3]) * di + b2[3];
        op[4] = (a4 + (float)sv[4]) * di + b2[4];
    }
}

extern "C" void kernel_launch(void* const* d_in, const int* in_sizes, int n_in,
                              void* d_out, int out_size, void* d_ws, size_t ws_size,
                              hipStream_t stream) {
    const float* x   = (const float*)d_in[0];
    const int*  eidx = (const int*)d_in[1];
    const float* W1 = (const float*)d_in[4];
    const float* b1 = (const float*)d_in[5];
    const float* W2 = (const float*)d_in[6];
    const float* b2 = (const float*)d_in[7];
    float* out = (float*)d_out;

    const int N = in_sizes[0] / 5;
    const int E = in_sizes[1] / 2;
    const int* src = eidx;
    const int* dst = eidx + E;

    const int B = (N + VPB - 1) / VPB;       // 391
    const int NBLK_E = (E + EPB - 1) / EPB;  // 512

    // workspace: pairs[B*CAP] xs[8N fp16] h2s[8N fp16] jinfo[N] bpos[B]
    int*      pairs = (int*)d_ws;
    _Float16* xs    = (_Float16*)(pairs + (size_t)B * CAP);
    _Float16* h2s   = xs + (size_t)8 * N;
    unsigned int* jinfo = (unsigned int*)(h2s + (size_t)8 * N);
    int*      bpos  = (int*)(jinfo + N);

    // g2 grid: 64-block groups covering 8 buckets x 8 sub-blocks,
    // so XCD(block%8) == bucket%8; ceil(B/8) groups.
    const int gG = ((B + 7) / 8) * 64;       // 49*64 = 3136

    k_init <<<(B + TPB - 1) / TPB, TPB, 0, stream>>>(B, bpos);
    k_scat <<<NBLK_E, SCT, 0, stream>>>(src, dst, E, B, bpos, pairs);
    k_pre  <<<B, DGT, 0, stream>>>(pairs, bpos, x, jinfo, xs, N);
    k_ag1  <<<B, 1024, 0, stream>>>(pairs, bpos, jinfo, xs, b1, W1, W2, h2s, N);
    k_g2   <<<gG, TPB, 0, stream>>>(pairs, jinfo, h2s, b2, out, N);
}